// Round 1
// baseline (315.631 us; speedup 1.0000x reference)
//
#include <hip/hip_runtime.h>
#include <math.h>

// Problem constants (fixed by the reference)
#define BATCH   32
#define DDIM    256
#define HWSZ    1024           // H*W = 32*32
#define NROWS   32768          // B*H*W
#define KCODES  1024

// Tiling
#define BN      64             // rows per block
#define BK      128            // codes per K-tile
#define BD      32             // d-chunk staged in LDS
#define NTHREADS 256

// ---------------------------------------------------------------------------
// Kernel 1: per-code squared norms ||e_k||^2  +  zero the loss slot
// ---------------------------------------------------------------------------
__global__ __launch_bounds__(256)
void vq_wnorm(const float* __restrict__ weight, float* __restrict__ wnorm,
              float* __restrict__ loss_slot) {
    const int tid  = threadIdx.x;
    const int lane = tid & 63;
    const int code = blockIdx.x * 4 + (tid >> 6);
    float4 v = *(const float4*)(weight + (size_t)code * DDIM + lane * 4);
    float s = v.x * v.x + v.y * v.y + v.z * v.z + v.w * v.w;
    #pragma unroll
    for (int off = 1; off < 64; off <<= 1) s += __shfl_xor(s, off);
    if (lane == 0) wnorm[code] = s;
    if (blockIdx.x == 0 && tid == 0) *loss_slot = 0.0f;
}

// ---------------------------------------------------------------------------
// Kernel 2: fused distance GEMM + argmin + gather + transpose-out + loss
// Each block: 64 consecutive rows (one batch image slice), all 1024 codes.
// ---------------------------------------------------------------------------
__global__ __launch_bounds__(NTHREADS, 2)
void vq_main(const float* __restrict__ latent, const float* __restrict__ weight,
             const float* __restrict__ wnorm, float* __restrict__ out) {
    __shared__ __align__(16) float As[BD][BN];    // 8 KB  (d-major, rows contiguous)
    __shared__ __align__(16) float Ws[BD][BK];    // 16 KB (d-major, codes contiguous)
    __shared__ int   sIdx[BN];
    __shared__ float sRed[4];

    const int tid = threadIdx.x;
    const int blk = blockIdx.x;
    const int tx  = tid & 15;          // code group: 16 groups x 8 codes
    const int ty  = tid >> 4;          // row group : 16 groups x 4 rows
    const int b   = blk >> 4;          // 16 blocks per batch image
    const int hw0 = (blk & 15) * BN;   // starting h*W+w within the image
    const float* lat_b = latent + (size_t)b * DDIM * HWSZ;

    // ---- pass 0: row squared norms xn[r] for this thread's 4 rows ----
    float xn[4] = {0.f, 0.f, 0.f, 0.f};
    for (int dc = 0; dc < DDIM / BD; ++dc) {
        __syncthreads();
        #pragma unroll
        for (int i = 0; i < 2; ++i) {
            int idx = tid + i * NTHREADS;
            int dd = idx >> 4, f4 = idx & 15;
            *(float4*)&As[dd][f4 * 4] =
                *(const float4*)(lat_b + (size_t)(dc * BD + dd) * HWSZ + hw0 + f4 * 4);
        }
        __syncthreads();
        #pragma unroll 8
        for (int dd = 0; dd < BD; ++dd) {
            float4 a = *(const float4*)&As[dd][ty * 4];
            xn[0] += a.x * a.x; xn[1] += a.y * a.y;
            xn[2] += a.z * a.z; xn[3] += a.w * a.w;
        }
    }

    // ---- main loop: K-tiles of 128 codes ----
    float best[4] = {INFINITY, INFINITY, INFINITY, INFINITY};
    int   bidx[4] = {0, 0, 0, 0};

    for (int kt = 0; kt < KCODES / BK; ++kt) {
        const int k0 = kt * BK;
        float acc[4][8];
        #pragma unroll
        for (int r = 0; r < 4; ++r)
            #pragma unroll
            for (int c = 0; c < 8; ++c) acc[r][c] = 0.f;

        for (int dc = 0; dc < DDIM / BD; ++dc) {
            const int d0 = dc * BD;
            __syncthreads();
            // stage A chunk: 64 rows x 32 d
            #pragma unroll
            for (int i = 0; i < 2; ++i) {
                int idx = tid + i * NTHREADS;
                int dd = idx >> 4, f4 = idx & 15;
                *(float4*)&As[dd][f4 * 4] =
                    *(const float4*)(lat_b + (size_t)(d0 + dd) * HWSZ + hw0 + f4 * 4);
            }
            // stage W chunk (transposed): 128 codes x 32 d
            #pragma unroll
            for (int i = 0; i < 4; ++i) {
                int idx = tid + i * NTHREADS;
                int kl = idx >> 3, df = idx & 7;
                float4 v = *(const float4*)(weight + (size_t)(k0 + kl) * DDIM + d0 + df * 4);
                Ws[df * 4 + 0][kl] = v.x;
                Ws[df * 4 + 1][kl] = v.y;
                Ws[df * 4 + 2][kl] = v.z;
                Ws[df * 4 + 3][kl] = v.w;
            }
            __syncthreads();

            #pragma unroll 8
            for (int dd = 0; dd < BD; ++dd) {
                float4 a  = *(const float4*)&As[dd][ty * 4];
                float4 w0 = *(const float4*)&Ws[dd][tx * 4];
                float4 w1 = *(const float4*)&Ws[dd][64 + tx * 4];
                float av[4] = {a.x, a.y, a.z, a.w};
                float wv[8] = {w0.x, w0.y, w0.z, w0.w, w1.x, w1.y, w1.z, w1.w};
                #pragma unroll
                for (int r = 0; r < 4; ++r)
                    #pragma unroll
                    for (int c = 0; c < 8; ++c)
                        acc[r][c] += av[r] * wv[c];
            }
        }

        // distances + running argmin (codes ascend: group A = k0+tx*4+c, B = +64)
        #pragma unroll
        for (int c = 0; c < 8; ++c) {
            const int kg = k0 + ((c < 4) ? (tx * 4 + c) : (64 + tx * 4 + (c - 4)));
            const float wn = wnorm[kg];
            #pragma unroll
            for (int r = 0; r < 4; ++r) {
                float dist = (xn[r] + wn) - 2.0f * acc[r][c];
                if (dist < best[r] || (dist == best[r] && kg < bidx[r])) {
                    best[r] = dist; bidx[r] = kg;
                }
            }
        }
    }

    // ---- reduce argmin across the 16 code-threads sharing each row ----
    #pragma unroll
    for (int j = 0; j < 4; ++j) {
        float bd = best[j];
        int   bi = bidx[j];
        #pragma unroll
        for (int off = 1; off < 16; off <<= 1) {
            float od = __shfl_xor(bd, off);
            int   oi = __shfl_xor(bi, off);
            if (od < bd || (od == bd && oi < bi)) { bd = od; bi = oi; }
        }
        if (tx == 0) sIdx[ty * 4 + j] = bi;
    }
    __syncthreads();

    // ---- epilogue: gather codes, write transposed output, commitment loss ----
    const int hwl  = tid & 63;
    const int wv   = tid >> 6;
    const int ksel = sIdx[hwl];
    const float* wrow = weight + (size_t)ksel * DDIM;
    float lsum = 0.f;
    #pragma unroll 4
    for (int it = 0; it < 64; ++it) {
        int d = it * 4 + wv;
        size_t off = (size_t)d * HWSZ + hw0 + hwl;
        float x = lat_b[off];
        float q = wrow[d];                 // scattered, L2-resident (1 MB codebook)
        out[(size_t)b * DDIM * HWSZ + off] = q;
        float df = q - x;
        lsum += df * df;
    }
    #pragma unroll
    for (int off = 1; off < 64; off <<= 1) lsum += __shfl_xor(lsum, off);
    if ((tid & 63) == 0) sRed[tid >> 6] = lsum;
    __syncthreads();
    if (tid == 0) {
        float t = sRed[0] + sRed[1] + sRed[2] + sRed[3];
        atomicAdd(out + (size_t)NROWS * DDIM, t * (1.0f / ((float)NROWS * (float)DDIM)));
    }
}

// ---------------------------------------------------------------------------
extern "C" void kernel_launch(void* const* d_in, const int* in_sizes, int n_in,
                              void* d_out, int out_size, void* d_ws, size_t ws_size,
                              hipStream_t stream) {
    const float* latent = (const float*)d_in[0];   // (32,256,32,32) f32
    const float* weight = (const float*)d_in[1];   // (1024,256)     f32
    float* out   = (float*)d_out;                  // 8388608 out + 1 loss
    float* wnorm = (float*)d_ws;                   // 1024 floats scratch

    vq_wnorm<<<KCODES / 4, 256, 0, stream>>>(weight, wnorm, out + (size_t)NROWS * DDIM);
    vq_main<<<NROWS / BN, NTHREADS, 0, stream>>>(latent, weight, wnorm, out);
}

// Round 6
// 285.367 us; speedup vs baseline: 1.1061x; 1.1061x over previous
//
#include <hip/hip_runtime.h>
#include <math.h>
#include <stdint.h>

#define DDIM   256
#define HWSZ   1024
#define NROWS  32768
#define KCODES 1024
#define BN     64
#define BK     128
#define BD     32
#define NT     256
#define WSP    132    // padded Ws row stride (breaks 512B bank alignment; 16B-aligned)

// ws layout: [0,4096) f32 wnorm[1024]; [4096, 4096+262144) u64 keys[32768]
#define WS_WNORM 0
#define WS_KEYS  4096
#define WS_NEED  (4096 + NROWS * 8)

__device__ __forceinline__ uint32_t fbits(float f) { return __float_as_uint(f); }

// ---------------------------------------------------------------------------
// k1: per-code squared norms + zero the loss slot   (round-1 proven, verbatim)
// ---------------------------------------------------------------------------
__global__ __launch_bounds__(256)
void vq_wnorm(const float* __restrict__ weight, float* __restrict__ wnorm,
              float* __restrict__ loss_slot) {
  const int tid  = threadIdx.x;
  const int lane = tid & 63;
  const int code = blockIdx.x * 4 + (tid >> 6);
  float4 v = *(const float4*)(weight + (size_t)code * DDIM + lane * 4);
  float s = v.x * v.x + v.y * v.y + v.z * v.z + v.w * v.w;
#pragma unroll
  for (int off = 1; off < 64; off <<= 1) s += __shfl_xor(s, off);
  if (lane == 0) wnorm[code] = s;
  if (blockIdx.x == 0 && tid == 0) *loss_slot = 0.0f;
}

// ---------------------------------------------------------------------------
// k2: f32 distances, ROUND-1 ARITHMETIC VERBATIM (incl. ||x||^2 coarse grid).
// Block = 64 rows x 256 codes (quarter q); global merge via u64 atomicMin:
// key = (orderflip(dist) << 32) | code  ->  min dist, lowest index on ties,
// exactly the reference's argmin-first-occurrence semantics.
// ---------------------------------------------------------------------------
__global__ __launch_bounds__(NT, 4)
void vq_dist(const float* __restrict__ latent, const float* __restrict__ weight,
             const float* __restrict__ wnorm,
             unsigned long long* __restrict__ keys) {
  __shared__ __align__(16) float As[BD][BN];    // 8 KB
  __shared__ __align__(16) float Ws[BD][WSP];   // 16.9 KB padded

  const int tid = threadIdx.x;
  const int tx  = tid & 15;            // code group: 16 groups x 8 codes
  const int ty  = tid >> 4;            // row group : 16 groups x 4 rows
  const int rb  = blockIdx.x >> 2;     // row-block 0..511
  const int q   = blockIdx.x & 3;      // code quarter 0..3
  const int b   = rb >> 4;
  const int hw0 = (rb & 15) * BN;
  const float* lat_b = latent + (size_t)b * DDIM * HWSZ;

  // ---- pass 0: row squared norms xn[r] (round-1 verbatim) ----
  float xn[4] = {0.f, 0.f, 0.f, 0.f};
  for (int dc = 0; dc < DDIM / BD; ++dc) {
    __syncthreads();
#pragma unroll
    for (int i = 0; i < 2; ++i) {
      int idx = tid + i * NT;
      int dd = idx >> 4, f4 = idx & 15;
      *(float4*)&As[dd][f4 * 4] =
          *(const float4*)(lat_b + (size_t)(dc * BD + dd) * HWSZ + hw0 + f4 * 4);
    }
    __syncthreads();
#pragma unroll 8
    for (int dd = 0; dd < BD; ++dd) {
      float4 a = *(const float4*)&As[dd][ty * 4];
      xn[0] += a.x * a.x; xn[1] += a.y * a.y;
      xn[2] += a.z * a.z; xn[3] += a.w * a.w;
    }
  }

  float best[4] = {INFINITY, INFINITY, INFINITY, INFINITY};
  int   bidx[4] = {0, 0, 0, 0};

  for (int kt = 0; kt < 2; ++kt) {
    const int k0 = q * 256 + kt * BK;
    float acc[4][8];
#pragma unroll
    for (int r = 0; r < 4; ++r)
#pragma unroll
      for (int c = 0; c < 8; ++c) acc[r][c] = 0.f;

    for (int dc = 0; dc < DDIM / BD; ++dc) {
      const int d0 = dc * BD;
      __syncthreads();
#pragma unroll
      for (int i = 0; i < 2; ++i) {
        int idx = tid + i * NT;
        int dd = idx >> 4, f4 = idx & 15;
        *(float4*)&As[dd][f4 * 4] =
            *(const float4*)(lat_b + (size_t)(d0 + dd) * HWSZ + hw0 + f4 * 4);
      }
#pragma unroll
      for (int i = 0; i < 4; ++i) {
        int idx = tid + i * NT;
        int kl = idx >> 3, df = idx & 7;
        float4 v = *(const float4*)(weight + (size_t)(k0 + kl) * DDIM + d0 + df * 4);
        Ws[df * 4 + 0][kl] = v.x;
        Ws[df * 4 + 1][kl] = v.y;
        Ws[df * 4 + 2][kl] = v.z;
        Ws[df * 4 + 3][kl] = v.w;
      }
      __syncthreads();

#pragma unroll 8
      for (int dd = 0; dd < BD; ++dd) {
        float4 a  = *(const float4*)&As[dd][ty * 4];
        float4 w0 = *(const float4*)&Ws[dd][tx * 4];
        float4 w1 = *(const float4*)&Ws[dd][64 + tx * 4];
        float av[4] = {a.x, a.y, a.z, a.w};
        float wv[8] = {w0.x, w0.y, w0.z, w0.w, w1.x, w1.y, w1.z, w1.w};
#pragma unroll
        for (int r = 0; r < 4; ++r)
#pragma unroll
          for (int c = 0; c < 8; ++c)
            acc[r][c] += av[r] * wv[c];
      }
    }

    // distances on the reference's coarse grid (round-1 expression, verbatim)
#pragma unroll
    for (int c = 0; c < 8; ++c) {
      const int kg = k0 + ((c < 4) ? (tx * 4 + c) : (64 + tx * 4 + (c - 4)));
      const float wn = wnorm[kg];
#pragma unroll
      for (int r = 0; r < 4; ++r) {
        float dist = (xn[r] + wn) - 2.0f * acc[r][c];
        if (dist < best[r] || (dist == best[r] && kg < bidx[r])) {
          best[r] = dist; bidx[r] = kg;
        }
      }
    }
  }

  // reduce argmin across the 16 code-threads per row; global fold via atomicMin
#pragma unroll
  for (int j = 0; j < 4; ++j) {
    float bd = best[j];
    int   bi = bidx[j];
#pragma unroll
    for (int off = 1; off < 16; off <<= 1) {
      float od = __shfl_xor(bd, off);
      int   oi = __shfl_xor(bi, off);
      if (od < bd || (od == bd && oi < bi)) { bd = od; bi = oi; }
    }
    if (tx == 0) {
      uint32_t db   = fbits(bd);
      uint32_t flip = (db & 0x80000000u) ? ~db : (db | 0x80000000u);
      unsigned long long key =
          ((unsigned long long)flip << 32) | (unsigned long long)(uint32_t)bi;
      atomicMin(&keys[rb * 64 + ty * 4 + j], key);
    }
  }
}

// ---------------------------------------------------------------------------
// k3: keys -> idx, gather codes, transposed coalesced output, loss
// (round-1 vq_out proven body + LDS idx stage)
// ---------------------------------------------------------------------------
__global__ __launch_bounds__(256)
void vq_emit(const float* __restrict__ latent, const float* __restrict__ weight,
             const unsigned long long* __restrict__ keys, float* __restrict__ out) {
  __shared__ int   sIdx[64];
  __shared__ float sRed[4];
  const int t   = threadIdx.x;
  const int blk = blockIdx.x;
  const int b   = blk >> 4;
  const int hw0 = (blk & 15) * 64;
  if (t < 64) sIdx[t] = (int)(keys[blk * 64 + t] & 0x3FFull);
  __syncthreads();

  const int hw4  = (t & 15) * 4;
  const int dgrp = t >> 4;
  const float* lat_b = latent + (size_t)b * DDIM * HWSZ;
  float* out_b = out + (size_t)b * DDIM * HWSZ;
  const float* w0 = weight + (size_t)sIdx[hw4 + 0] * DDIM;
  const float* w1 = weight + (size_t)sIdx[hw4 + 1] * DDIM;
  const float* w2 = weight + (size_t)sIdx[hw4 + 2] * DDIM;
  const float* w3 = weight + (size_t)sIdx[hw4 + 3] * DDIM;
  float lsum = 0.f;
#pragma unroll
  for (int it = 0; it < 16; ++it) {
    const int d = it * 16 + dgrp;
    float4 xv = *(const float4*)(lat_b + (size_t)d * HWSZ + hw0 + hw4);
    float q0 = w0[d], q1 = w1[d], q2 = w2[d], q3 = w3[d];
    *(float4*)(out_b + (size_t)d * HWSZ + hw0 + hw4) = make_float4(q0, q1, q2, q3);
    float e0 = q0 - xv.x, e1 = q1 - xv.y, e2 = q2 - xv.z, e3 = q3 - xv.w;
    lsum += e0 * e0 + e1 * e1 + e2 * e2 + e3 * e3;
  }
#pragma unroll
  for (int s = 1; s < 64; s <<= 1) lsum += __shfl_xor(lsum, s);
  if ((t & 63) == 0) sRed[t >> 6] = lsum;
  __syncthreads();
  if (t == 0) {
    float tot = sRed[0] + sRed[1] + sRed[2] + sRed[3];
    atomicAdd(out + (size_t)NROWS * DDIM, tot * (1.0f / 8388608.0f));
  }
}

// ---------------------------------------------------------------------------
// k2m: fallback if ws too small for keys — ROUND-1 PASSING KERNEL VERBATIM
// (only layout change: Ws padded stride; arithmetic untouched)
// ---------------------------------------------------------------------------
__global__ __launch_bounds__(NT, 2)
void vq_mono(const float* __restrict__ latent, const float* __restrict__ weight,
             const float* __restrict__ wnorm, float* __restrict__ out) {
  __shared__ __align__(16) float As[BD][BN];
  __shared__ __align__(16) float Ws[BD][WSP];
  __shared__ int   sIdx[BN];
  __shared__ float sRed[4];

  const int tid = threadIdx.x;
  const int blk = blockIdx.x;
  const int tx  = tid & 15;
  const int ty  = tid >> 4;
  const int b   = blk >> 4;
  const int hw0 = (blk & 15) * BN;
  const float* lat_b = latent + (size_t)b * DDIM * HWSZ;

  float xn[4] = {0.f, 0.f, 0.f, 0.f};
  for (int dc = 0; dc < DDIM / BD; ++dc) {
    __syncthreads();
#pragma unroll
    for (int i = 0; i < 2; ++i) {
      int idx = tid + i * NT;
      int dd = idx >> 4, f4 = idx & 15;
      *(float4*)&As[dd][f4 * 4] =
          *(const float4*)(lat_b + (size_t)(dc * BD + dd) * HWSZ + hw0 + f4 * 4);
    }
    __syncthreads();
#pragma unroll 8
    for (int dd = 0; dd < BD; ++dd) {
      float4 a = *(const float4*)&As[dd][ty * 4];
      xn[0] += a.x * a.x; xn[1] += a.y * a.y;
      xn[2] += a.z * a.z; xn[3] += a.w * a.w;
    }
  }

  float best[4] = {INFINITY, INFINITY, INFINITY, INFINITY};
  int   bidx[4] = {0, 0, 0, 0};

  for (int kt = 0; kt < KCODES / BK; ++kt) {
    const int k0 = kt * BK;
    float acc[4][8];
#pragma unroll
    for (int r = 0; r < 4; ++r)
#pragma unroll
      for (int c = 0; c < 8; ++c) acc[r][c] = 0.f;

    for (int dc = 0; dc < DDIM / BD; ++dc) {
      const int d0 = dc * BD;
      __syncthreads();
#pragma unroll
      for (int i = 0; i < 2; ++i) {
        int idx = tid + i * NT;
        int dd = idx >> 4, f4 = idx & 15;
        *(float4*)&As[dd][f4 * 4] =
            *(const float4*)(lat_b + (size_t)(d0 + dd) * HWSZ + hw0 + f4 * 4);
      }
#pragma unroll
      for (int i = 0; i < 4; ++i) {
        int idx = tid + i * NT;
        int kl = idx >> 3, df = idx & 7;
        float4 v = *(const float4*)(weight + (size_t)(k0 + kl) * DDIM + d0 + df * 4);
        Ws[df * 4 + 0][kl] = v.x;
        Ws[df * 4 + 1][kl] = v.y;
        Ws[df * 4 + 2][kl] = v.z;
        Ws[df * 4 + 3][kl] = v.w;
      }
      __syncthreads();

#pragma unroll 8
      for (int dd = 0; dd < BD; ++dd) {
        float4 a  = *(const float4*)&As[dd][ty * 4];
        float4 w0 = *(const float4*)&Ws[dd][tx * 4];
        float4 w1 = *(const float4*)&Ws[dd][64 + tx * 4];
        float av[4] = {a.x, a.y, a.z, a.w};
        float wv[8] = {w0.x, w0.y, w0.z, w0.w, w1.x, w1.y, w1.z, w1.w};
#pragma unroll
        for (int r = 0; r < 4; ++r)
#pragma unroll
          for (int c = 0; c < 8; ++c)
            acc[r][c] += av[r] * wv[c];
      }
    }

#pragma unroll
    for (int c = 0; c < 8; ++c) {
      const int kg = k0 + ((c < 4) ? (tx * 4 + c) : (64 + tx * 4 + (c - 4)));
      const float wn = wnorm[kg];
#pragma unroll
      for (int r = 0; r < 4; ++r) {
        float dist = (xn[r] + wn) - 2.0f * acc[r][c];
        if (dist < best[r] || (dist == best[r] && kg < bidx[r])) {
          best[r] = dist; bidx[r] = kg;
        }
      }
    }
  }

#pragma unroll
  for (int j = 0; j < 4; ++j) {
    float bd = best[j];
    int   bi = bidx[j];
#pragma unroll
    for (int off = 1; off < 16; off <<= 1) {
      float od = __shfl_xor(bd, off);
      int   oi = __shfl_xor(bi, off);
      if (od < bd || (od == bd && oi < bi)) { bd = od; bi = oi; }
    }
    if (tx == 0) sIdx[ty * 4 + j] = bi;
  }
  __syncthreads();

  const int hwl = tid & 63;
  const int wv  = tid >> 6;
  const int ksel = sIdx[hwl];
  const float* wrow = weight + (size_t)ksel * DDIM;
  float lsum = 0.f;
#pragma unroll 4
  for (int it = 0; it < 64; ++it) {
    int d = it * 4 + wv;
    size_t off = (size_t)d * HWSZ + hw0 + hwl;
    float x = lat_b[off];
    float qv = wrow[d];
    out[(size_t)b * DDIM * HWSZ + off] = qv;
    float df = qv - x;
    lsum += df * df;
  }
#pragma unroll
  for (int off = 1; off < 64; off <<= 1) lsum += __shfl_xor(lsum, off);
  if ((tid & 63) == 0) sRed[tid >> 6] = lsum;
  __syncthreads();
  if (tid == 0) {
    float t = sRed[0] + sRed[1] + sRed[2] + sRed[3];
    atomicAdd(out + (size_t)NROWS * DDIM, t * (1.0f / ((float)NROWS * (float)DDIM)));
  }
}

// ---------------------------------------------------------------------------
extern "C" void kernel_launch(void* const* d_in, const int* in_sizes, int n_in,
                              void* d_out, int out_size, void* d_ws, size_t ws_size,
                              hipStream_t stream) {
  const float* latent = (const float*)d_in[0];   // (32,256,32,32) f32
  const float* weight = (const float*)d_in[1];   // (1024,256)     f32
  float* out   = (float*)d_out;                  // 8388608 + 1 (loss)
  char*  ws    = (char*)d_ws;
  float* wnorm = (float*)(ws + WS_WNORM);

  vq_wnorm<<<KCODES / 4, 256, 0, stream>>>(weight, wnorm, out + (size_t)NROWS * DDIM);

  if (ws_size >= (size_t)WS_NEED) {
    unsigned long long* keys = (unsigned long long*)(ws + WS_KEYS);
    hipMemsetAsync(ws + WS_KEYS, 0xFF, (size_t)NROWS * 8, stream);
    vq_dist<<<2048, NT, 0, stream>>>(latent, weight, wnorm, keys);
    vq_emit<<< 512, 256, 0, stream>>>(latent, weight, keys, out);
  } else {
    vq_mono<<< 512, NT, 0, stream>>>(latent, weight, wnorm, out);
  }
}